// Round 1
// baseline (845.029 us; speedup 1.0000x reference)
//
#include <hip/hip_runtime.h>
#include <math.h>

#define NFFT 256
#define NBINS 129
#define HOP 64
#define NFRAMES 65
#define NB 64
#define LX 4096
#define LH 2048
#define LY 1024
#define NCH 64
#define NBR 3
#define NE 8

#define POOLED_BYTES (NB * NBINS * 4)

// ---------------- STFT magnitude + frame-mean pooling ----------------
// grid (65 frames, 64 batch), 192 threads. Naive 256-pt DFT, 129 bins.
__global__ __launch_bounds__(192) void stft_kernel(const float* __restrict__ x,
                                                   float* __restrict__ pooled) {
    __shared__ float xw[NFFT];
    __shared__ float ct[NFFT];
    __shared__ float st[NFFT];
    const int f = blockIdx.x, b = blockIdx.y;
    const int tid = threadIdx.x;

    for (int n = tid; n < NFFT; n += 192) {
        float ang = (float)(2.0 * 3.14159265358979323846 / 256.0) * (float)n;
        float s, c;
        sincosf(ang, &s, &c);
        ct[n] = c;
        st[n] = s;
        float win = 0.5f - 0.5f * c;              // Hann, same angle
        int q = f * HOP + n - 128;                // position in x coords
        int xi = q < 0 ? -q : (q >= LX ? (2 * LX - 2 - q) : q);  // reflect
        xw[n] = x[b * LX + xi] * win;
    }
    __syncthreads();

    const int k = tid;
    if (k < NBINS) {
        float re = 0.f, im = 0.f;
        for (int n = 0; n < NFFT; ++n) {
            int idx = (k * n) & 255;
            float v = xw[n];
            re += v * ct[idx];
            im += v * st[idx];   // sign irrelevant for magnitude
        }
        float mag = sqrtf(re * re + im * im);
        atomicAdd(&pooled[b * NBINS + k], mag);
    }
}

// ---------------- Gating MLP + top-2 softmax ----------------
// grid 64 (one block per batch row), 256 threads.
__global__ __launch_bounds__(256) void gating_kernel(
    const float* __restrict__ pooled,
    const float* __restrict__ Wg1, const float* __restrict__ bg1,
    const float* __restrict__ Wg2, const float* __restrict__ bg2,
    const float* __restrict__ Wg3, const float* __restrict__ bg3,
    int* __restrict__ inds, float* __restrict__ wts) {
    __shared__ float pl[NBINS];
    __shared__ float h1[256];
    __shared__ float h2[128];
    __shared__ float lg[NE];
    const int b = blockIdx.x, tid = threadIdx.x;

    if (tid < NBINS) pl[tid] = pooled[b * NBINS + tid] * (1.0f / (float)NFRAMES);
    __syncthreads();
    {
        float s = bg1[tid];
        for (int k = 0; k < NBINS; ++k) s += pl[k] * Wg1[k * 256 + tid];
        h1[tid] = fmaxf(s, 0.f);
    }
    __syncthreads();
    if (tid < 128) {
        float s = bg2[tid];
        for (int k = 0; k < 256; ++k) s += h1[k] * Wg2[k * 128 + tid];
        h2[tid] = fmaxf(s, 0.f);
    }
    __syncthreads();
    if (tid < NE) {
        float s = bg3[tid];
        for (int k = 0; k < 128; ++k) s += h2[k] * Wg3[k * NE + tid];
        lg[tid] = s;
    }
    __syncthreads();
    if (tid == 0) {
        int i0 = 0;
        float v0 = lg[0];
        for (int i = 1; i < NE; ++i)
            if (lg[i] > v0) { v0 = lg[i]; i0 = i; }
        int i1 = -1;
        float v1 = -3.0e38f;
        for (int i = 0; i < NE; ++i) {
            if (i == i0) continue;
            if (lg[i] > v1) { v1 = lg[i]; i1 = i; }
        }
        float e1 = expf(v1 - v0);
        float w0 = 1.f / (1.f + e1);
        inds[b * 2 + 0] = i0;
        inds[b * 2 + 1] = i1;
        wts[b * 2 + 0] = w0;
        wts[b * 2 + 1] = e1 * w0;
    }
}

// ---------------- Expert two-conv path, top-2 dispatched ----------------
// grid (u-tiles=8, branch=3, batch=64), 256 threads.
// Per block: both selected experts for (b, branch, 128-wide u tile).
#define UT 128
#define CCH 16
#define HST 258
#define XSEG 520

__global__ __launch_bounds__(256) void expert_kernel(
    const float* __restrict__ x,
    const float* __restrict__ wa3, const float* __restrict__ ba3,
    const float* __restrict__ wb3, const float* __restrict__ bb3,
    const float* __restrict__ wa5, const float* __restrict__ ba5,
    const float* __restrict__ wb5, const float* __restrict__ bb5,
    const float* __restrict__ wa7, const float* __restrict__ ba7,
    const float* __restrict__ wb7, const float* __restrict__ bb7,
    const int* __restrict__ inds, const float* __restrict__ wts,
    float* __restrict__ out) {
    __shared__ float xl[XSEG];
    __shared__ float hl[CCH * HST];
    __shared__ float wbl[NCH * CCH * 3];
    __shared__ float wal[CCH * 7];
    __shared__ float bal[CCH];

    const int u0 = blockIdx.x * UT;
    const int br = blockIdx.y;
    const int b = blockIdx.z;
    const int tid = threadIdx.x;

    const float *wa, *ba, *wb, *bb;
    int ksz;
    if (br == 0)      { wa = wa3; ba = ba3; wb = wb3; bb = bb3; ksz = 3; }
    else if (br == 1) { wa = wa5; ba = ba5; wb = wb5; bb = bb5; ksz = 5; }
    else              { wa = wa7; ba = ba7; wb = wb7; bb = bb7; ksz = 7; }
    const int pad = ksz >> 1;

    const int t0 = 2 * u0 - 1;          // first h position needed
    const int x0 = 2 * t0 - pad;        // first x index needed
    const int xcnt = 513 + ksz;

    for (int j = tid; j < xcnt; j += 256) {
        int xi = x0 + j;
        xl[j] = (xi >= 0 && xi < LX) ? x[b * LX + xi] : 0.f;   // conv zero-pad
    }

    const int l5 = tid & 31;   // u lane (32 consecutive u per store run)
    const int cb = tid >> 5;   // c2 base 0..7

    float fin[8][4];
#pragma unroll
    for (int j = 0; j < 8; ++j)
#pragma unroll
        for (int m = 0; m < 4; ++m) fin[j][m] = 0.f;

    for (int slot = 0; slot < 2; ++slot) {
        const int e = inds[b * 2 + slot];
        const float wj = wts[b * 2 + slot];

        float acc[8][4];
#pragma unroll
        for (int j = 0; j < 8; ++j) {
            float bbv = bb[e * NCH + cb + 8 * j];
#pragma unroll
            for (int m = 0; m < 4; ++m) acc[j][m] = bbv;
        }

        for (int c0 = 0; c0 < NCH; c0 += CCH) {
            __syncthreads();   // protect LDS from previous chunk's readers
            // stage first-conv weights/bias for this channel chunk
            if (tid < CCH * ksz) {
                int cl = tid / ksz, i = tid - cl * ksz;
                wal[cl * 7 + i] = wa[(e * NCH + c0 + cl) * ksz + i];
            }
            if (tid < CCH) bal[tid] = ba[e * NCH + c0 + tid];
            // stage second-conv weights: wbl[c2*48 + cl*3 + i]
            for (int idx = tid; idx < NCH * CCH * 3; idx += 256) {
                int c2 = idx / 48, r = idx - c2 * 48;
                wbl[idx] = wb[(e * NCH + c2) * (NCH * 3) + c0 * 3 + r];
            }
            __syncthreads();

            // phase A: first conv + relu into LDS (positions t0..t0+256)
            for (int idx = tid; idx < CCH * 257; idx += 256) {
                int cl = idx / 257, p = idx - cl * 257;
                int t = t0 + p;
                float hv = 0.f;
                if (t >= 0 && t < LH) {
                    float s = bal[cl];
                    for (int i = 0; i < ksz; ++i)
                        s += wal[cl * 7 + i] * xl[2 * p + i];
                    hv = fmaxf(s, 0.f);
                }
                hl[cl * HST + p] = hv;
            }
            __syncthreads();

            // phase C: second conv, register-tiled 8 c2 x 4 u per thread
#pragma unroll
            for (int cl = 0; cl < CCH; ++cl) {
                float h0[4], h1v[4], h2v[4];
#pragma unroll
                for (int m = 0; m < 4; ++m) {
                    int p = 2 * (l5 + 32 * m);
                    h0[m] = hl[cl * HST + p];
                    h1v[m] = hl[cl * HST + p + 1];
                    h2v[m] = hl[cl * HST + p + 2];
                }
#pragma unroll
                for (int j = 0; j < 8; ++j) {
                    int c2 = cb + 8 * j;
                    float w0 = wbl[c2 * 48 + cl * 3 + 0];
                    float w1 = wbl[c2 * 48 + cl * 3 + 1];
                    float w2 = wbl[c2 * 48 + cl * 3 + 2];
#pragma unroll
                    for (int m = 0; m < 4; ++m)
                        acc[j][m] += w0 * h0[m] + w1 * h1v[m] + w2 * h2v[m];
                }
            }
        }

#pragma unroll
        for (int j = 0; j < 8; ++j)
#pragma unroll
            for (int m = 0; m < 4; ++m)
                fin[j][m] += wj * fmaxf(acc[j][m], 0.f);
    }

#pragma unroll
    for (int j = 0; j < 8; ++j) {
        int c2 = cb + 8 * j;
        long row = (long)(b * 192 + br * 64 + c2) * LY;
#pragma unroll
        for (int m = 0; m < 4; ++m) {
            int u = u0 + l5 + 32 * m;
            out[row + u] = fin[j][m];
        }
    }
}

extern "C" void kernel_launch(void* const* d_in, const int* in_sizes, int n_in,
                              void* d_out, int out_size, void* d_ws, size_t ws_size,
                              hipStream_t stream) {
    const float* x   = (const float*)d_in[0];
    const float* Wg1 = (const float*)d_in[1];
    const float* bg1 = (const float*)d_in[2];
    const float* Wg2 = (const float*)d_in[3];
    const float* bg2 = (const float*)d_in[4];
    const float* Wg3 = (const float*)d_in[5];
    const float* bg3 = (const float*)d_in[6];
    const float* wa3 = (const float*)d_in[7];
    const float* ba3 = (const float*)d_in[8];
    const float* wb3 = (const float*)d_in[9];
    const float* bb3 = (const float*)d_in[10];
    const float* wa5 = (const float*)d_in[11];
    const float* ba5 = (const float*)d_in[12];
    const float* wb5 = (const float*)d_in[13];
    const float* bb5 = (const float*)d_in[14];
    const float* wa7 = (const float*)d_in[15];
    const float* ba7 = (const float*)d_in[16];
    const float* wb7 = (const float*)d_in[17];
    const float* bb7 = (const float*)d_in[18];

    float* pooled = (float*)d_ws;
    int* inds = (int*)((char*)d_ws + POOLED_BYTES);
    float* wts = (float*)((char*)d_ws + POOLED_BYTES + 512);

    hipMemsetAsync(d_ws, 0, POOLED_BYTES, stream);
    stft_kernel<<<dim3(NFRAMES, NB), 192, 0, stream>>>(x, pooled);
    gating_kernel<<<NB, 256, 0, stream>>>(pooled, Wg1, bg1, Wg2, bg2, Wg3, bg3,
                                          inds, wts);
    expert_kernel<<<dim3(LY / UT, NBR, NB), 256, 0, stream>>>(
        x, wa3, ba3, wb3, bb3, wa5, ba5, wb5, bb5, wa7, ba7, wb7, bb7,
        inds, wts, (float*)d_out);
}